// Round 1
// baseline (749.332 us; speedup 1.0000x reference)
//
#include <hip/hip_runtime.h>
#include <cstdint>

#define NB 32768        // rows per entity
#define HH 512          // hidden dim

typedef __attribute__((ext_vector_type(8))) _Float16 f16x8;
typedef __attribute__((ext_vector_type(4))) float f32x4;
typedef __attribute__((ext_vector_type(4))) unsigned short us4v;

static __device__ __forceinline__ unsigned short f2h(float f) {
  _Float16 h = (_Float16)f;
  return __builtin_bit_cast(unsigned short, h);
}
static __device__ __forceinline__ float h2f(unsigned short u) {
  return (float)__builtin_bit_cast(_Float16, u);
}
static __device__ __forceinline__ float wred(float v) {
#pragma unroll
  for (int off = 32; off > 0; off >>= 1) v += __shfl_xor(v, off);
  return v;
}
static __device__ __forceinline__ float sigm(float x) { return 1.f / (1.f + __expf(-x)); }
static __device__ __forceinline__ float tanh_fast(float x) {
  return 1.f - 2.f / (__expf(2.f * x) + 1.f);
}
static __device__ __forceinline__ float softplus_fast(float x) {
  return fmaxf(x, 0.f) + log1pf(__expf(-fabsf(x)));
}

// ================= prep: weight casts + w2re/w2rr + rho consts =====================
__global__ __launch_bounds__(256) void prep_k(
    const float* __restrict__ W1, const float* __restrict__ Wv,
    const float* __restrict__ Wt, const float* __restrict__ Wre,
    const float* __restrict__ Wrr, const float* __restrict__ b2,
    const float* __restrict__ W2,
    unsigned short* __restrict__ W1h, unsigned short* __restrict__ Wvh,
    unsigned short* __restrict__ Wth,
    float* __restrict__ w2re, float* __restrict__ w2rr, float* __restrict__ rho_c) {
  __shared__ float red[4];
  const int bx = blockIdx.x, t = threadIdx.x;
  if (bx < 2560) {
    int i = bx * 256 + t;            // 0 .. 655359
    if (i < 262144) W1h[i] = f2h(W1[i]);
    else if (i < 393216) Wvh[i - 262144] = f2h(Wv[i - 262144]);
    else Wth[i - 393216] = f2h(Wt[i - 393216]);
  } else if (bx < 2562) {
    // w2sel[k] = sum_j wsel[j] * W2[j,k]   (fp32 exact, coalesced over k)
    const float* ws = (bx == 2560) ? Wre : Wrr;
    float* wd = (bx == 2560) ? w2re : w2rr;
    float a0 = 0.f, a1 = 0.f;
    for (int j = 0; j < 512; ++j) {
      float wv = ws[j];
      a0 += wv * W2[j * 512 + t];
      a1 += wv * W2[j * 512 + t + 256];
    }
    wd[t] = a0;
    wd[t + 256] = a1;
  } else {
    // rho_c[0] = b2.wre ; rho_c[1] = b2.wrr
    const float* ws = (bx == 2562) ? Wre : Wrr;
    float p = b2[t] * ws[t] + b2[t + 256] * ws[t + 256];
    p = wred(p);
    if ((t & 63) == 0) red[t >> 6] = p;
    __syncthreads();
    if (t == 0) rho_c[bx - 2562] = red[0] + red[1] + red[2] + red[3];
  }
}

// ================= M2 = Wsel @ W2 (fp16 out) + bcat = bsel + b2.Wsel_row ===========
__global__ __launch_bounds__(256) void m2_k(
    const float* __restrict__ Wv, const float* __restrict__ Wt,
    const float* __restrict__ W2, const float* __restrict__ b2,
    const float* __restrict__ bv, const float* __restrict__ bt,
    unsigned short* __restrict__ M2v, unsigned short* __restrict__ M2t,
    float* __restrict__ bcv, float* __restrict__ bct) {
  __shared__ float rowL[512];
  __shared__ float red[4];
  const int b = blockIdx.x, t = threadIdx.x;
  int n; const float* src; unsigned short* dst; const float* badd; float* bdst;
  if (b < 256) { n = b; src = Wv + (long)n * 512; dst = M2v + (long)n * 512; badd = bv; bdst = bcv; }
  else { n = b - 256; src = Wt + (long)n * 512; dst = M2t + (long)n * 512; badd = bt; bdst = bct; }
  rowL[t] = src[t]; rowL[t + 256] = src[t + 256];
  __syncthreads();
  float a0 = 0.f, a1 = 0.f;
  for (int j = 0; j < 512; ++j) {
    float rv = rowL[j];
    a0 += rv * W2[(long)j * 512 + t];
    a1 += rv * W2[(long)j * 512 + t + 256];
  }
  dst[t] = f2h(a0);
  dst[t + 256] = f2h(a1);
  float p = b2[t] * rowL[t] + b2[t + 256] * rowL[t + 256];
  p = wred(p);
  if ((t & 63) == 0) red[t >> 6] = p;
  __syncthreads();
  if (t == 0) bdst[n] = badd[n] + red[0] + red[1] + red[2] + red[3];
}

// ================= fused GEMM: T in LDS, heads computed in-place ===================
// One block = 32 rows of one entity. Phase 0: X fp32 -> swizzled fp16 Xh (LDS) +
// rho X-part. Phase 1: T = relu(Xh@W1h^T+b1) -> swizzled fp16 Ts (LDS) + rho T-part.
// Phase 2: Out = Xh@Wx^T + Ts@Wm^T + bias. B fragments come straight from L2-resident
// weight matrices (read-once per block) -> NO barriers inside the MFMA loops.
// LDS swizzle: byte ^= (row&7)<<4 spreads the stride-1KB ds_read_b128 column reads
// across 8 16B slots -> 2-way bank aliasing (free, m136).
template <int NF>
static __device__ __forceinline__ void gemm_half(
    const unsigned short* As,                 // LDS, swizzled [32][512] fp16
    const unsigned short* __restrict__ Bg,    // global [N][512] fp16 (L2-resident)
    int nw, int cg, int cl, f32x4 (&acc)[2][NF]) {
#pragma unroll 2
  for (int kb = 0; kb < 16; ++kb) {
    const int kcol = kb * 32 + cg * 8;
    f16x8 af[2];
#pragma unroll
    for (int i = 0; i < 2; ++i) {
      const int row = i * 16 + cl;
      const int bo = (row * 1024 + kcol * 2) ^ ((row & 7) << 4);
      af[i] = *(const f16x8*)((const char*)As + bo);
    }
#pragma unroll
    for (int j = 0; j < NF; ++j) {
      const f16x8 bj = *(const f16x8*)(Bg + (long)(nw + j * 16 + cl) * HH + kcol);
#pragma unroll
      for (int i = 0; i < 2; ++i)
        acc[i][j] = __builtin_amdgcn_mfma_f32_16x16x32_f16(af[i], bj, acc[i][j], 0, 0, 0);
    }
  }
}

__global__ __launch_bounds__(256, 2) void fused_k(
    const float* __restrict__ x0, const float* __restrict__ x1,
    const float* __restrict__ x2, const unsigned short* __restrict__ W1h,
    const float* __restrict__ b1, const float* __restrict__ wre,
    const float* __restrict__ wrr, const float* __restrict__ w2re,
    const float* __restrict__ w2rr, const unsigned short* __restrict__ Wvh,
    const unsigned short* __restrict__ Wth, const unsigned short* __restrict__ M2v,
    const unsigned short* __restrict__ M2t, const float* __restrict__ bcv,
    const float* __restrict__ bct, unsigned short* __restrict__ Uh,
    unsigned short* __restrict__ Ut, unsigned short* __restrict__ THh,
    float* __restrict__ rho_raw) {
  __shared__ unsigned short Xh[32 * 512];   // 32 KB, swizzled
  __shared__ unsigned short Ts[32 * 512];   // 32 KB, swizzled
  __shared__ float rxp[32];                 // X . wsel per row (fp32 exact)
  __shared__ float rtp[32];                 // T . w2sel per row
  const int tid = threadIdx.x, lane = tid & 63, w = tid >> 6;
  const int cg = lane >> 4, cl = lane & 15;
  const int bx = blockIdx.x;
  const int ent = bx >> 10;                      // 0=h, 1=t, 2=r
  const long mloc = (long)(bx & 1023) * 32;
  const float* X = (ent == 0) ? x0 : (ent == 1) ? x1 : x2;
  const float* wsel = (ent < 2) ? wre : wrr;
  const float* w2sel = (ent < 2) ? w2re : w2rr;

  if (tid < 32) rtp[tid] = 0.f;

  // ---- phase 0: X fp32 -> fp16 Xh (swizzled), rho X-part in fp32 ----
  {
    const int col = lane * 8;  // each wave covers one full 512-col row per q
    const f32x4 wv0 = *(const f32x4*)(wsel + col);
    const f32x4 wv1 = *(const f32x4*)(wsel + col + 4);
#pragma unroll
    for (int q = 0; q < 8; ++q) {
      const int row = q * 4 + w;
      const float* gp = X + (mloc + row) * HH + col;
      const f32x4 a0 = *(const f32x4*)gp;
      const f32x4 a1 = *(const f32x4*)(gp + 4);
      f16x8 hx;
      hx[0] = (_Float16)a0[0]; hx[1] = (_Float16)a0[1];
      hx[2] = (_Float16)a0[2]; hx[3] = (_Float16)a0[3];
      hx[4] = (_Float16)a1[0]; hx[5] = (_Float16)a1[1];
      hx[6] = (_Float16)a1[2]; hx[7] = (_Float16)a1[3];
      const int bo = (row * 1024 + col * 2) ^ ((row & 7) << 4);
      *(f16x8*)((char*)Xh + bo) = hx;
      float p = a0[0] * wv0[0] + a0[1] * wv0[1] + a0[2] * wv0[2] + a0[3] * wv0[3] +
                a1[0] * wv1[0] + a1[1] * wv1[1] + a1[2] * wv1[2] + a1[3] * wv1[3];
      p = wred(p);
      if (lane == 0) rxp[row] = p;
    }
  }
  __syncthreads();

  // ---- phase 1: T = relu(Xh @ W1h^T + b1), 32x512, K=512; wave owns 128 cols ----
  {
    f32x4 acc[2][8] = {};
    gemm_half<8>(Xh, W1h, w * 128, cg, cl, acc);
    float drow[2][4] = {{0.f, 0.f, 0.f, 0.f}, {0.f, 0.f, 0.f, 0.f}};
#pragma unroll
    for (int i = 0; i < 2; ++i)
#pragma unroll
      for (int j = 0; j < 8; ++j) {
        const int col = w * 128 + j * 16 + cl;
        const float bc = b1[col], w2v = w2sel[col];
#pragma unroll
        for (int r = 0; r < 4; ++r) {
          const int row = i * 16 + cg * 4 + r;
          const float v = fmaxf(acc[i][j][r] + bc, 0.f);
          const int bo = (row * 1024 + col * 2) ^ ((row & 7) << 4);
          *(unsigned short*)((char*)Ts + bo) = f2h(v);
          drow[i][r] += v * w2v;
        }
      }
#pragma unroll
    for (int i = 0; i < 2; ++i)
#pragma unroll
      for (int r = 0; r < 4; ++r) {
        float s = drow[i][r];
        s += __shfl_xor(s, 1); s += __shfl_xor(s, 2);
        s += __shfl_xor(s, 4); s += __shfl_xor(s, 8);
        if (cl == 0) atomicAdd(&rtp[i * 16 + cg * 4 + r], s);
      }
  }
  __syncthreads();

  if (tid < 32) rho_raw[(long)ent * NB + mloc + tid] = rxp[tid] + rtp[tid];

  // ---- phase 2: heads. K=1024 as two K=512 halves over Xh then Ts ----
  if (ent < 2) {
    unsigned short* Out = ent ? Ut : Uh;   // ent0 = h, ent1 = t
    f32x4 acc[2][4] = {};
    gemm_half<4>(Xh, Wvh, w * 64, cg, cl, acc);
    gemm_half<4>(Ts, M2v, w * 64, cg, cl, acc);
#pragma unroll
    for (int i = 0; i < 2; ++i)
#pragma unroll
      for (int j = 0; j < 4; ++j) {
        const int col = w * 64 + j * 16 + cl;
        const float bc = bcv[col];
#pragma unroll
        for (int r = 0; r < 4; ++r)
          Out[(mloc + i * 16 + cg * 4 + r) * 256 + col] = f2h(acc[i][j][r] + bc);
      }
  } else {
    f32x4 acc[2][8] = {};
    gemm_half<8>(Xh, Wth, w * 128, cg, cl, acc);
    gemm_half<8>(Ts, M2t, w * 128, cg, cl, acc);
#pragma unroll
    for (int i = 0; i < 2; ++i)
#pragma unroll
      for (int j = 0; j < 8; ++j) {
        const int col = w * 128 + j * 16 + cl;
        const float bc = bct[col];
#pragma unroll
        for (int r = 0; r < 4; ++r)
          THh[(mloc + i * 16 + cg * 4 + r) * (long)HH + col] = f2h(acc[i][j][r] + bc);
      }
  }
}

// ================= Givens chain: wave-parallel linear scan =========================
__device__ __forceinline__ void givens_pass(float v[4], const float c[4],
                                            const float s[4], int lane) {
  float vn3 = __shfl_down(v[0], 1);
  float A = 1.f, Bc = 0.f;
#pragma unroll
  for (int k = 0; k < 4; ++k) {
    float vnext = (k < 3) ? v[k + 1] : vn3;
    bool skip = (lane == 63) && (k == 3);
    if (!skip) { Bc = s[k] * Bc + c[k] * vnext; A = s[k] * A; }
  }
  float iA = A, iB = Bc;
#pragma unroll
  for (int off = 1; off < 64; off <<= 1) {
    float pA = __shfl_up(iA, off);
    float pB = __shfl_up(iB, off);
    if (lane >= off) { iB = iA * pB + iB; iA = iA * pA; }
  }
  float eA = __shfl_up(iA, 1);
  float eB = __shfl_up(iB, 1);
  if (lane == 0) { eA = 1.f; eB = 0.f; }
  float v0g = __shfl(v[0], 0);
  float K = eA * v0g + eB;
  float out[4];
#pragma unroll
  for (int k = 0; k < 4; ++k) {
    float vnext = (k < 3) ? v[k + 1] : vn3;
    bool skip = (lane == 63) && (k == 3);
    if (!skip) {
      out[k] = c[k] * K - s[k] * vnext;
      K = s[k] * K + c[k] * vnext;
    } else out[k] = 0.f;
  }
  float K255 = __shfl(K, 63);
  float c255 = __shfl(c[3], 63);
  float s255 = __shfl(s[3], 63);
  float o0 = __shfl(out[0], 0);
  if (lane == 63) out[3] = c255 * K255 - s255 * o0;
  if (lane == 0) out[0] = s255 * K255 + c255 * o0;
  v[0] = out[0]; v[1] = out[1]; v[2] = out[2]; v[3] = out[3];
}

// ================= final per-row kernel: one wave per row ==========================
__global__ __launch_bounds__(256) void final_k(
    const unsigned short* __restrict__ Uh, const unsigned short* __restrict__ Ut,
    const unsigned short* __restrict__ THh, const float* __restrict__ rho_raw,
    const float* __restrict__ rho_c, const float* __restrict__ sim,
    const float* __restrict__ bre, const float* __restrict__ brr,
    const float* __restrict__ ga_rho, const float* __restrict__ gb_rho,
    const float* __restrict__ ga_phi, const float* __restrict__ gb_phi,
    float* __restrict__ out) {
  const int lane = threadIdx.x & 63;
  const int b = blockIdx.x * 4 + (threadIdx.x >> 6);

  us4v h4 = *(const us4v*)(Uh + (long)b * 256 + lane * 4);
  us4v t4 = *(const us4v*)(Ut + (long)b * 256 + lane * 4);
  us4v a4 = *(const us4v*)(THh + (long)b * 512 + lane * 4);
  us4v b4 = *(const us4v*)(THh + (long)b * 512 + 256 + lane * 4);

  const float PI_F = 3.14159265358979f;
  float vh[4], vt[4], cA[4], sA[4], cB[4], sB[4];
#pragma unroll
  for (int k = 0; k < 4; ++k) {
    vh[k] = h2f(h4[k]); vt[k] = h2f(t4[k]);
    float aa = PI_F * tanh_fast(h2f(a4[k]));
    sA[k] = __sinf(aa); cA[k] = __cosf(aa);
    float ab = PI_F * tanh_fast(h2f(b4[k]));
    sB[k] = __sinf(ab); cB[k] = __cosf(ab);
  }

  float ssq = wred(vh[0] * vh[0] + vh[1] * vh[1] + vh[2] * vh[2] + vh[3] * vh[3]);
  float invh = 1.f / (sqrtf(ssq) + 1e-8f);
  float u[4], v[4];
#pragma unroll
  for (int k = 0; k < 4; ++k) { u[k] = vh[k] * invh; v[k] = u[k]; }

  givens_pass(v, cA, sA, lane);  // rotations 0..255
  givens_pass(v, cB, sB, lane);  // rotations 256..511

  float ssr = wred(v[0] * v[0] + v[1] * v[1] + v[2] * v[2] + v[3] * v[3]);
  float invr = 1.f / (sqrtf(ssr) + 1e-8f);
  float ur[4];
#pragma unroll
  for (int k = 0; k < 4; ++k) ur[k] = v[k] * invr;

  float dt = wred(u[0] * ur[0] + u[1] * ur[1] + u[2] * ur[2] + u[3] * ur[3]);
  dt = fminf(fmaxf(dt, -1.f + 1e-8f), 1.f - 1e-8f);
  float omega = acosf(dt);
  float sino = sqrtf(fmaxf(1.f - dt * dt, 0.f));
  float sb = sim[b];
  float gphi = sigm(ga_phi[0] * sb + gb_phi[0]);
  float s1, s2;
  if (omega > 0.001f) {
    s1 = __sinf((1.f - gphi) * omega) / (sino + 1e-8f);
    s2 = __sinf(gphi * omega) / (sino + 1e-8f);
  } else {
    s1 = 1.f - gphi;
    s2 = gphi;
  }
  float up[4];
#pragma unroll
  for (int k = 0; k < 4; ++k) up[k] = s1 * u[k] + s2 * ur[k];
  float ssp = wred(up[0] * up[0] + up[1] * up[1] + up[2] * up[2] + up[3] * up[3]);
  float invp = 1.f / (sqrtf(ssp) + 1e-8f);
  float sst = wred(vt[0] * vt[0] + vt[1] * vt[1] + vt[2] * vt[2] + vt[3] * vt[3]);
  float invt = 1.f / (sqrtf(sst) + 1e-8f);
  float dp = wred(up[0] * vt[0] + up[1] * vt[1] + up[2] * vt[2] + up[3] * vt[3]) * invp * invt;

  float rh = fminf(fmaxf(softplus_fast(rho_raw[b] + rho_c[0] + bre[0]), 0.f), 9.f);
  float rt = fminf(fmaxf(softplus_fast(rho_raw[NB + b] + rho_c[0] + bre[0]), 0.f), 9.f);
  float dR = rho_raw[2 * NB + b] + rho_c[1] + brr[0];
  float grho = sigm(ga_rho[0] * sb + gb_rho[0]);
  float rp = fminf(fmaxf(rh + dR * grho, 0.f), 9.f);
  float er = __expf(rp), eri = __expf(-rp);
  float et = __expf(rt), eti = __expf(-rt);
  float score = -0.25f * (er + eri) * (et + eti) + 0.25f * (er - eri) * (et - eti) * dp;
  if (lane == 0) out[b] = score;
}

extern "C" void kernel_launch(void* const* d_in, const int* in_sizes, int n_in,
                              void* d_out, int out_size, void* d_ws, size_t ws_size,
                              hipStream_t stream) {
  (void)in_sizes; (void)n_in;
  const float* x0 = (const float*)d_in[0];   // ent_embed (h)
  const float* x2 = (const float*)d_in[1];   // rel_embed (r)
  const float* x1 = (const float*)d_in[2];   // ent_label (t)
  const float* sim = (const float*)d_in[3];
  const float* Wv = (const float*)d_in[4];
  const float* bv = (const float*)d_in[5];
  const float* Wre = (const float*)d_in[6];
  const float* bre = (const float*)d_in[7];
  const float* Wrr = (const float*)d_in[8];
  const float* brr = (const float*)d_in[9];
  const float* Wt = (const float*)d_in[10];
  const float* bt = (const float*)d_in[11];
  const float* ga_rho = (const float*)d_in[12];
  const float* gb_rho = (const float*)d_in[13];
  const float* ga_phi = (const float*)d_in[14];
  const float* gb_phi = (const float*)d_in[15];
  const float* W1 = (const float*)d_in[16];
  const float* b1 = (const float*)d_in[17];
  const float* W2 = (const float*)d_in[18];
  const float* b2 = (const float*)d_in[19];

  const size_t NEEDED = 69606408ULL;  // Tbig eliminated: 169.7 MB -> 69.6 MB
  if (ws_size < NEEDED) {  // clean diagnostic failure instead of OOB fault
    (void)hipMemsetAsync(d_out, 0, (size_t)out_size * sizeof(float), stream);
    return;
  }
  char* ws = (char*)d_ws;
  unsigned short* Uh = (unsigned short*)ws;                 // 16 MB (NB x 256 f16)
  unsigned short* Ut = (unsigned short*)(ws + 16777216);    // 16 MB
  unsigned short* THh = (unsigned short*)(ws + 33554432);   // 32 MB (NB x 512 f16)
  float* rho_raw = (float*)(ws + 67108864);                 // 384 KB (3*NB f32)
  unsigned short* W1h = (unsigned short*)(ws + 67502080);   // 512 KB (live through fused_k!)
  unsigned short* Wvh = (unsigned short*)(ws + 68026368);   // 256 KB
  unsigned short* Wth = (unsigned short*)(ws + 68288512);   // 512 KB
  unsigned short* M2v = (unsigned short*)(ws + 68812800);   // 256 KB
  unsigned short* M2t = (unsigned short*)(ws + 69074944);   // 512 KB (no W1h alias now)
  float* w2re = (float*)(ws + 69599232);                    // 2 KB
  float* w2rr = (float*)(ws + 69601280);                    // 2 KB
  float* bcv = (float*)(ws + 69603328);                     // 1 KB
  float* bct = (float*)(ws + 69604352);                     // 2 KB
  float* rho_c = (float*)(ws + 69606400);                   // 8 B

  prep_k<<<dim3(2564), dim3(256), 0, stream>>>(
      W1, Wv, Wt, Wre, Wrr, b2, W2, W1h, Wvh, Wth, w2re, w2rr, rho_c);

  m2_k<<<dim3(768), dim3(256), 0, stream>>>(Wv, Wt, W2, b2, bv, bt, M2v, M2t, bcv, bct);

  fused_k<<<dim3(3072), dim3(256), 0, stream>>>(
      x0, x1, x2, W1h, b1, Wre, Wrr, w2re, w2rr, Wvh, Wth, M2v, M2t, bcv, bct,
      Uh, Ut, THh, rho_raw);

  final_k<<<dim3(8192), dim3(256), 0, stream>>>(
      Uh, Ut, THh, rho_raw, rho_c, sim, bre, brr, ga_rho, gb_rho, ga_phi, gb_phi,
      (float*)d_out);
}

// Round 2
// 734.970 us; speedup vs baseline: 1.0195x; 1.0195x over previous
//
#include <hip/hip_runtime.h>
#include <cstdint>

#define NB 32768        // rows per entity
#define HH 512          // hidden dim

typedef __attribute__((ext_vector_type(8))) _Float16 f16x8;
typedef __attribute__((ext_vector_type(4))) float f32x4;
typedef __attribute__((ext_vector_type(4))) unsigned short us4v;

static __device__ __forceinline__ unsigned short f2h(float f) {
  _Float16 h = (_Float16)f;
  return __builtin_bit_cast(unsigned short, h);
}
static __device__ __forceinline__ float h2f(unsigned short u) {
  return (float)__builtin_bit_cast(_Float16, u);
}
static __device__ __forceinline__ float wred(float v) {
#pragma unroll
  for (int off = 32; off > 0; off >>= 1) v += __shfl_xor(v, off);
  return v;
}
static __device__ __forceinline__ float sigm(float x) { return 1.f / (1.f + __expf(-x)); }
static __device__ __forceinline__ float tanh_fast(float x) {
  return 1.f - 2.f / (__expf(2.f * x) + 1.f);
}
static __device__ __forceinline__ float softplus_fast(float x) {
  return fmaxf(x, 0.f) + log1pf(__expf(-fabsf(x)));
}

// ================= prep: weight casts + w2re/w2rr + rho consts =====================
__global__ __launch_bounds__(256) void prep_k(
    const float* __restrict__ W1, const float* __restrict__ Wv,
    const float* __restrict__ Wt, const float* __restrict__ Wre,
    const float* __restrict__ Wrr, const float* __restrict__ b2,
    const float* __restrict__ W2,
    unsigned short* __restrict__ W1h, unsigned short* __restrict__ Wvh,
    unsigned short* __restrict__ Wth,
    float* __restrict__ w2re, float* __restrict__ w2rr, float* __restrict__ rho_c) {
  __shared__ float red[4];
  const int bx = blockIdx.x, t = threadIdx.x;
  if (bx < 2560) {
    int i = bx * 256 + t;            // 0 .. 655359
    if (i < 262144) W1h[i] = f2h(W1[i]);
    else if (i < 393216) Wvh[i - 262144] = f2h(Wv[i - 262144]);
    else Wth[i - 393216] = f2h(Wt[i - 393216]);
  } else if (bx < 2562) {
    // w2sel[k] = sum_j wsel[j] * W2[j,k]   (fp32 exact, coalesced over k)
    const float* ws = (bx == 2560) ? Wre : Wrr;
    float* wd = (bx == 2560) ? w2re : w2rr;
    float a0 = 0.f, a1 = 0.f;
    for (int j = 0; j < 512; ++j) {
      float wv = ws[j];
      a0 += wv * W2[j * 512 + t];
      a1 += wv * W2[j * 512 + t + 256];
    }
    wd[t] = a0;
    wd[t + 256] = a1;
  } else {
    // rho_c[0] = b2.wre ; rho_c[1] = b2.wrr
    const float* ws = (bx == 2562) ? Wre : Wrr;
    float p = b2[t] * ws[t] + b2[t + 256] * ws[t + 256];
    p = wred(p);
    if ((t & 63) == 0) red[t >> 6] = p;
    __syncthreads();
    if (t == 0) rho_c[bx - 2562] = red[0] + red[1] + red[2] + red[3];
  }
}

// ================= M2 = Wsel @ W2 (fp16 out) + bcat = bsel + b2.Wsel_row ===========
__global__ __launch_bounds__(256) void m2_k(
    const float* __restrict__ Wv, const float* __restrict__ Wt,
    const float* __restrict__ W2, const float* __restrict__ b2,
    const float* __restrict__ bv, const float* __restrict__ bt,
    unsigned short* __restrict__ M2v, unsigned short* __restrict__ M2t,
    float* __restrict__ bcv, float* __restrict__ bct) {
  __shared__ float rowL[512];
  __shared__ float red[4];
  const int b = blockIdx.x, t = threadIdx.x;
  int n; const float* src; unsigned short* dst; const float* badd; float* bdst;
  if (b < 256) { n = b; src = Wv + (long)n * 512; dst = M2v + (long)n * 512; badd = bv; bdst = bcv; }
  else { n = b - 256; src = Wt + (long)n * 512; dst = M2t + (long)n * 512; badd = bt; bdst = bct; }
  rowL[t] = src[t]; rowL[t + 256] = src[t + 256];
  __syncthreads();
  float a0 = 0.f, a1 = 0.f;
  for (int j = 0; j < 512; ++j) {
    float rv = rowL[j];
    a0 += rv * W2[(long)j * 512 + t];
    a1 += rv * W2[(long)j * 512 + t + 256];
  }
  dst[t] = f2h(a0);
  dst[t + 256] = f2h(a1);
  float p = b2[t] * rowL[t] + b2[t + 256] * rowL[t + 256];
  p = wred(p);
  if ((t & 63) == 0) red[t >> 6] = p;
  __syncthreads();
  if (t == 0) bdst[n] = badd[n] + red[0] + red[1] + red[2] + red[3];
}

// ================= fused GEMM: T in LDS, heads computed in-place ===================
// One block = 32 rows of one entity, 8 waves (512 thr), 2 blocks/CU -> 4 waves/SIMD.
// B operands stream from L2-resident weights with an explicit DEPTH-2 register
// pipeline (bpipe[2][NF], all indices static after full unroll) so each fragment
// has ~2 kb-iterations of MFMA across 4 interleaved waves to cover L2 latency.
template <int MI, int NF>
static __device__ __forceinline__ void gemm_half(
    const unsigned short* As,                 // LDS, swizzled [32][512] fp16
    const unsigned short* __restrict__ Bg,    // global [N][512] fp16 (L2-resident)
    int nw, int cg, int cl, f32x4 (&acc)[MI][NF]) {
  const unsigned short* Bp = Bg + (long)(nw + cl) * HH + cg * 8;
  f16x8 bpipe[2][NF];
#pragma unroll
  for (int j = 0; j < NF; ++j) {
    bpipe[0][j] = *(const f16x8*)(Bp + (long)(j * 16) * HH);
    bpipe[1][j] = *(const f16x8*)(Bp + (long)(j * 16) * HH + 32);
  }
#pragma unroll
  for (int kb = 0; kb < 16; ++kb) {
    const int kcol = kb * 32 + cg * 8;
    f16x8 af[MI];
#pragma unroll
    for (int i = 0; i < MI; ++i) {
      const int row = i * 16 + cl;
      const int bo = (row * 1024 + kcol * 2) ^ ((row & 7) << 4);
      af[i] = *(const f16x8*)((const char*)As + bo);
    }
    f16x8 bc[NF];
#pragma unroll
    for (int j = 0; j < NF; ++j) bc[j] = bpipe[kb & 1][j];
    if (kb < 14) {
#pragma unroll
      for (int j = 0; j < NF; ++j)
        bpipe[kb & 1][j] = *(const f16x8*)(Bp + (long)(j * 16) * HH + (kb + 2) * 32);
    }
    __builtin_amdgcn_s_setprio(1);
#pragma unroll
    for (int j = 0; j < NF; ++j)
#pragma unroll
      for (int i = 0; i < MI; ++i)
        acc[i][j] = __builtin_amdgcn_mfma_f32_16x16x32_f16(af[i], bc[j], acc[i][j], 0, 0, 0);
    __builtin_amdgcn_s_setprio(0);
  }
}

__global__ __launch_bounds__(512, 4) void fused_k(
    const float* __restrict__ x0, const float* __restrict__ x1,
    const float* __restrict__ x2, const unsigned short* __restrict__ W1h,
    const float* __restrict__ b1, const float* __restrict__ wre,
    const float* __restrict__ wrr, const float* __restrict__ w2re,
    const float* __restrict__ w2rr, const unsigned short* __restrict__ Wvh,
    const unsigned short* __restrict__ Wth, const unsigned short* __restrict__ M2v,
    const unsigned short* __restrict__ M2t, const float* __restrict__ bcv,
    const float* __restrict__ bct, unsigned short* __restrict__ Uh,
    unsigned short* __restrict__ Ut, unsigned short* __restrict__ THh,
    float* __restrict__ rho_raw) {
  __shared__ unsigned short Xh[32 * 512];   // 32 KB, swizzled
  __shared__ unsigned short Ts[32 * 512];   // 32 KB, swizzled
  __shared__ float rxp[32];                 // X . wsel per row (fp32 exact)
  __shared__ float rtp[32];                 // T . w2sel per row
  const int tid = threadIdx.x, lane = tid & 63, w = tid >> 6;
  const int cg = lane >> 4, cl = lane & 15;
  const int bx = blockIdx.x;
  const int ent = bx >> 10;                      // 0=h, 1=t, 2=r
  const long mloc = (long)(bx & 1023) * 32;
  const float* X = (ent == 0) ? x0 : (ent == 1) ? x1 : x2;
  const float* wsel = (ent < 2) ? wre : wrr;
  const float* w2sel = (ent < 2) ? w2re : w2rr;

  if (tid < 32) rtp[tid] = 0.f;

  // ---- phase 0: X fp32 -> fp16 Xh (swizzled), rho X-part in fp32 ----
  {
    const int col = lane * 8;  // each wave covers one full 512-col row per q
    const f32x4 wv0 = *(const f32x4*)(wsel + col);
    const f32x4 wv1 = *(const f32x4*)(wsel + col + 4);
#pragma unroll
    for (int q = 0; q < 4; ++q) {
      const int row = q * 8 + w;
      const float* gp = X + (mloc + row) * HH + col;
      const f32x4 a0 = *(const f32x4*)gp;
      const f32x4 a1 = *(const f32x4*)(gp + 4);
      f16x8 hx;
      hx[0] = (_Float16)a0[0]; hx[1] = (_Float16)a0[1];
      hx[2] = (_Float16)a0[2]; hx[3] = (_Float16)a0[3];
      hx[4] = (_Float16)a1[0]; hx[5] = (_Float16)a1[1];
      hx[6] = (_Float16)a1[2]; hx[7] = (_Float16)a1[3];
      const int bo = (row * 1024 + col * 2) ^ ((row & 7) << 4);
      *(f16x8*)((char*)Xh + bo) = hx;
      float p = a0[0] * wv0[0] + a0[1] * wv0[1] + a0[2] * wv0[2] + a0[3] * wv0[3] +
                a1[0] * wv1[0] + a1[1] * wv1[1] + a1[2] * wv1[2] + a1[3] * wv1[3];
      p = wred(p);
      if (lane == 0) rxp[row] = p;
    }
  }
  __syncthreads();

  // ---- phase 1: T = relu(Xh @ W1h^T + b1), 32x512, K=512; wave owns 64 cols ----
  {
    f32x4 acc[2][4] = {};
    gemm_half<2, 4>(Xh, W1h, w * 64, cg, cl, acc);
    float drow[2][4] = {{0.f, 0.f, 0.f, 0.f}, {0.f, 0.f, 0.f, 0.f}};
#pragma unroll
    for (int i = 0; i < 2; ++i)
#pragma unroll
      for (int j = 0; j < 4; ++j) {
        const int col = w * 64 + j * 16 + cl;
        const float bc = b1[col], w2v = w2sel[col];
#pragma unroll
        for (int r = 0; r < 4; ++r) {
          const int row = i * 16 + cg * 4 + r;
          const float v = fmaxf(acc[i][j][r] + bc, 0.f);
          const int bo = (row * 1024 + col * 2) ^ ((row & 7) << 4);
          *(unsigned short*)((char*)Ts + bo) = f2h(v);
          drow[i][r] += v * w2v;
        }
      }
#pragma unroll
    for (int i = 0; i < 2; ++i)
#pragma unroll
      for (int r = 0; r < 4; ++r) {
        float s = drow[i][r];
        s += __shfl_xor(s, 1); s += __shfl_xor(s, 2);
        s += __shfl_xor(s, 4); s += __shfl_xor(s, 8);
        if (cl == 0) atomicAdd(&rtp[i * 16 + cg * 4 + r], s);
      }
  }
  __syncthreads();

  if (tid < 32) rho_raw[(long)ent * NB + mloc + tid] = rxp[tid] + rtp[tid];

  // ---- phase 2: heads. K=1024 as two K=512 halves over Xh then Ts ----
  if (ent < 2) {
    unsigned short* Out = ent ? Ut : Uh;   // ent0 = h, ent1 = t
    f32x4 acc[2][2] = {};
    gemm_half<2, 2>(Xh, Wvh, w * 32, cg, cl, acc);
    gemm_half<2, 2>(Ts, M2v, w * 32, cg, cl, acc);
#pragma unroll
    for (int i = 0; i < 2; ++i)
#pragma unroll
      for (int j = 0; j < 2; ++j) {
        const int col = w * 32 + j * 16 + cl;
        const float bc = bcv[col];
#pragma unroll
        for (int r = 0; r < 4; ++r)
          Out[(mloc + i * 16 + cg * 4 + r) * 256 + col] = f2h(acc[i][j][r] + bc);
      }
  } else {
    f32x4 acc[2][4] = {};
    gemm_half<2, 4>(Xh, Wth, w * 64, cg, cl, acc);
    gemm_half<2, 4>(Ts, M2t, w * 64, cg, cl, acc);
#pragma unroll
    for (int i = 0; i < 2; ++i)
#pragma unroll
      for (int j = 0; j < 4; ++j) {
        const int col = w * 64 + j * 16 + cl;
        const float bc = bct[col];
#pragma unroll
        for (int r = 0; r < 4; ++r)
          THh[(mloc + i * 16 + cg * 4 + r) * (long)HH + col] = f2h(acc[i][j][r] + bc);
      }
  }
}

// ================= Givens chain: wave-parallel linear scan =========================
__device__ __forceinline__ void givens_pass(float v[4], const float c[4],
                                            const float s[4], int lane) {
  float vn3 = __shfl_down(v[0], 1);
  float A = 1.f, Bc = 0.f;
#pragma unroll
  for (int k = 0; k < 4; ++k) {
    float vnext = (k < 3) ? v[k + 1] : vn3;
    bool skip = (lane == 63) && (k == 3);
    if (!skip) { Bc = s[k] * Bc + c[k] * vnext; A = s[k] * A; }
  }
  float iA = A, iB = Bc;
#pragma unroll
  for (int off = 1; off < 64; off <<= 1) {
    float pA = __shfl_up(iA, off);
    float pB = __shfl_up(iB, off);
    if (lane >= off) { iB = iA * pB + iB; iA = iA * pA; }
  }
  float eA = __shfl_up(iA, 1);
  float eB = __shfl_up(iB, 1);
  if (lane == 0) { eA = 1.f; eB = 0.f; }
  float v0g = __shfl(v[0], 0);
  float K = eA * v0g + eB;
  float out[4];
#pragma unroll
  for (int k = 0; k < 4; ++k) {
    float vnext = (k < 3) ? v[k + 1] : vn3;
    bool skip = (lane == 63) && (k == 3);
    if (!skip) {
      out[k] = c[k] * K - s[k] * vnext;
      K = s[k] * K + c[k] * vnext;
    } else out[k] = 0.f;
  }
  float K255 = __shfl(K, 63);
  float c255 = __shfl(c[3], 63);
  float s255 = __shfl(s[3], 63);
  float o0 = __shfl(out[0], 0);
  if (lane == 63) out[3] = c255 * K255 - s255 * o0;
  if (lane == 0) out[0] = s255 * K255 + c255 * o0;
  v[0] = out[0]; v[1] = out[1]; v[2] = out[2]; v[3] = out[3];
}

// ================= final per-row kernel: one wave per row ==========================
__global__ __launch_bounds__(256) void final_k(
    const unsigned short* __restrict__ Uh, const unsigned short* __restrict__ Ut,
    const unsigned short* __restrict__ THh, const float* __restrict__ rho_raw,
    const float* __restrict__ rho_c, const float* __restrict__ sim,
    const float* __restrict__ bre, const float* __restrict__ brr,
    const float* __restrict__ ga_rho, const float* __restrict__ gb_rho,
    const float* __restrict__ ga_phi, const float* __restrict__ gb_phi,
    float* __restrict__ out) {
  const int lane = threadIdx.x & 63;
  const int b = blockIdx.x * 4 + (threadIdx.x >> 6);

  us4v h4 = *(const us4v*)(Uh + (long)b * 256 + lane * 4);
  us4v t4 = *(const us4v*)(Ut + (long)b * 256 + lane * 4);
  us4v a4 = *(const us4v*)(THh + (long)b * 512 + lane * 4);
  us4v b4 = *(const us4v*)(THh + (long)b * 512 + 256 + lane * 4);

  const float PI_F = 3.14159265358979f;
  float vh[4], vt[4], cA[4], sA[4], cB[4], sB[4];
#pragma unroll
  for (int k = 0; k < 4; ++k) {
    vh[k] = h2f(h4[k]); vt[k] = h2f(t4[k]);
    float aa = PI_F * tanh_fast(h2f(a4[k]));
    sA[k] = __sinf(aa); cA[k] = __cosf(aa);
    float ab = PI_F * tanh_fast(h2f(b4[k]));
    sB[k] = __sinf(ab); cB[k] = __cosf(ab);
  }

  float ssq = wred(vh[0] * vh[0] + vh[1] * vh[1] + vh[2] * vh[2] + vh[3] * vh[3]);
  float invh = 1.f / (sqrtf(ssq) + 1e-8f);
  float u[4], v[4];
#pragma unroll
  for (int k = 0; k < 4; ++k) { u[k] = vh[k] * invh; v[k] = u[k]; }

  givens_pass(v, cA, sA, lane);  // rotations 0..255
  givens_pass(v, cB, sB, lane);  // rotations 256..511

  float ssr = wred(v[0] * v[0] + v[1] * v[1] + v[2] * v[2] + v[3] * v[3]);
  float invr = 1.f / (sqrtf(ssr) + 1e-8f);
  float ur[4];
#pragma unroll
  for (int k = 0; k < 4; ++k) ur[k] = v[k] * invr;

  float dt = wred(u[0] * ur[0] + u[1] * ur[1] + u[2] * ur[2] + u[3] * ur[3]);
  dt = fminf(fmaxf(dt, -1.f + 1e-8f), 1.f - 1e-8f);
  float omega = acosf(dt);
  float sino = sqrtf(fmaxf(1.f - dt * dt, 0.f));
  float sb = sim[b];
  float gphi = sigm(ga_phi[0] * sb + gb_phi[0]);
  float s1, s2;
  if (omega > 0.001f) {
    s1 = __sinf((1.f - gphi) * omega) / (sino + 1e-8f);
    s2 = __sinf(gphi * omega) / (sino + 1e-8f);
  } else {
    s1 = 1.f - gphi;
    s2 = gphi;
  }
  float up[4];
#pragma unroll
  for (int k = 0; k < 4; ++k) up[k] = s1 * u[k] + s2 * ur[k];
  float ssp = wred(up[0] * up[0] + up[1] * up[1] + up[2] * up[2] + up[3] * up[3]);
  float invp = 1.f / (sqrtf(ssp) + 1e-8f);
  float sst = wred(vt[0] * vt[0] + vt[1] * vt[1] + vt[2] * vt[2] + vt[3] * vt[3]);
  float invt = 1.f / (sqrtf(sst) + 1e-8f);
  float dp = wred(up[0] * vt[0] + up[1] * vt[1] + up[2] * vt[2] + up[3] * vt[3]) * invp * invt;

  float rh = fminf(fmaxf(softplus_fast(rho_raw[b] + rho_c[0] + bre[0]), 0.f), 9.f);
  float rt = fminf(fmaxf(softplus_fast(rho_raw[NB + b] + rho_c[0] + bre[0]), 0.f), 9.f);
  float dR = rho_raw[2 * NB + b] + rho_c[1] + brr[0];
  float grho = sigm(ga_rho[0] * sb + gb_rho[0]);
  float rp = fminf(fmaxf(rh + dR * grho, 0.f), 9.f);
  float er = __expf(rp), eri = __expf(-rp);
  float et = __expf(rt), eti = __expf(-rt);
  float score = -0.25f * (er + eri) * (et + eti) + 0.25f * (er - eri) * (et - eti) * dp;
  if (lane == 0) out[b] = score;
}

extern "C" void kernel_launch(void* const* d_in, const int* in_sizes, int n_in,
                              void* d_out, int out_size, void* d_ws, size_t ws_size,
                              hipStream_t stream) {
  (void)in_sizes; (void)n_in;
  const float* x0 = (const float*)d_in[0];   // ent_embed (h)
  const float* x2 = (const float*)d_in[1];   // rel_embed (r)
  const float* x1 = (const float*)d_in[2];   // ent_label (t)
  const float* sim = (const float*)d_in[3];
  const float* Wv = (const float*)d_in[4];
  const float* bv = (const float*)d_in[5];
  const float* Wre = (const float*)d_in[6];
  const float* bre = (const float*)d_in[7];
  const float* Wrr = (const float*)d_in[8];
  const float* brr = (const float*)d_in[9];
  const float* Wt = (const float*)d_in[10];
  const float* bt = (const float*)d_in[11];
  const float* ga_rho = (const float*)d_in[12];
  const float* gb_rho = (const float*)d_in[13];
  const float* ga_phi = (const float*)d_in[14];
  const float* gb_phi = (const float*)d_in[15];
  const float* W1 = (const float*)d_in[16];
  const float* b1 = (const float*)d_in[17];
  const float* W2 = (const float*)d_in[18];
  const float* b2 = (const float*)d_in[19];

  const size_t NEEDED = 69606408ULL;
  if (ws_size < NEEDED) {  // clean diagnostic failure instead of OOB fault
    (void)hipMemsetAsync(d_out, 0, (size_t)out_size * sizeof(float), stream);
    return;
  }
  char* ws = (char*)d_ws;
  unsigned short* Uh = (unsigned short*)ws;                 // 16 MB (NB x 256 f16)
  unsigned short* Ut = (unsigned short*)(ws + 16777216);    // 16 MB
  unsigned short* THh = (unsigned short*)(ws + 33554432);   // 32 MB (NB x 512 f16)
  float* rho_raw = (float*)(ws + 67108864);                 // 384 KB (3*NB f32)
  unsigned short* W1h = (unsigned short*)(ws + 67502080);   // 512 KB (live through fused_k!)
  unsigned short* Wvh = (unsigned short*)(ws + 68026368);   // 256 KB
  unsigned short* Wth = (unsigned short*)(ws + 68288512);   // 512 KB
  unsigned short* M2v = (unsigned short*)(ws + 68812800);   // 256 KB
  unsigned short* M2t = (unsigned short*)(ws + 69074944);   // 512 KB (no W1h alias now)
  float* w2re = (float*)(ws + 69599232);                    // 2 KB
  float* w2rr = (float*)(ws + 69601280);                    // 2 KB
  float* bcv = (float*)(ws + 69603328);                     // 1 KB
  float* bct = (float*)(ws + 69604352);                     // 2 KB
  float* rho_c = (float*)(ws + 69606400);                   // 8 B

  prep_k<<<dim3(2564), dim3(256), 0, stream>>>(
      W1, Wv, Wt, Wre, Wrr, b2, W2, W1h, Wvh, Wth, w2re, w2rr, rho_c);

  m2_k<<<dim3(768), dim3(256), 0, stream>>>(Wv, Wt, W2, b2, bv, bt, M2v, M2t, bcv, bct);

  fused_k<<<dim3(3072), dim3(512), 0, stream>>>(
      x0, x1, x2, W1h, b1, Wre, Wrr, w2re, w2rr, Wvh, Wth, M2v, M2t, bcv, bct,
      Uh, Ut, THh, rho_raw);

  final_k<<<dim3(8192), dim3(256), 0, stream>>>(
      Uh, Ut, THh, rho_raw, rho_c, sim, bre, brr, ga_rho, gb_rho, ga_phi, gb_phi,
      (float*)d_out);
}

// Round 4
// 706.609 us; speedup vs baseline: 1.0605x; 1.0401x over previous
//
#include <hip/hip_runtime.h>
#include <cstdint>

#define NB 32768        // rows per entity
#define HH 512          // hidden dim

typedef __attribute__((ext_vector_type(8))) _Float16 f16x8;
typedef __attribute__((ext_vector_type(4))) float f32x4;
typedef __attribute__((ext_vector_type(4))) unsigned short us4v;

static __device__ __forceinline__ unsigned short f2h(float f) {
  _Float16 h = (_Float16)f;
  return __builtin_bit_cast(unsigned short, h);
}
static __device__ __forceinline__ float h2f(unsigned short u) {
  return (float)__builtin_bit_cast(_Float16, u);
}
static __device__ __forceinline__ void gl_lds16(const void* g, void* l) {
  __builtin_amdgcn_global_load_lds(
      (const __attribute__((address_space(1))) unsigned int*)g,
      (__attribute__((address_space(3))) unsigned int*)l, 16, 0, 0);
}
static __device__ __forceinline__ float wred(float v) {
#pragma unroll
  for (int off = 32; off > 0; off >>= 1) v += __shfl_xor(v, off);
  return v;
}
static __device__ __forceinline__ float sigm(float x) { return 1.f / (1.f + __expf(-x)); }
static __device__ __forceinline__ float tanh_fast(float x) {
  return 1.f - 2.f / (__expf(2.f * x) + 1.f);
}
static __device__ __forceinline__ float softplus_fast(float x) {
  return fmaxf(x, 0.f) + log1pf(__expf(-fabsf(x)));
}

// ================= prep: weight casts + w2re/w2rr + rho consts + rho zero ==========
__global__ __launch_bounds__(256) void prep_k(
    const float* __restrict__ W1, const float* __restrict__ Wv,
    const float* __restrict__ Wt, const float* __restrict__ Wre,
    const float* __restrict__ Wrr, const float* __restrict__ b2,
    const float* __restrict__ W2,
    unsigned short* __restrict__ W1h, unsigned short* __restrict__ Wvh,
    unsigned short* __restrict__ Wth, float* __restrict__ rho_raw,
    float* __restrict__ w2re, float* __restrict__ w2rr, float* __restrict__ rho_c) {
  __shared__ float red[4];
  const int bx = blockIdx.x, t = threadIdx.x;
  if (bx < 2560) {
    int i = bx * 256 + t;            // 0 .. 655359
    if (i < 98304) rho_raw[i] = 0.f;
    if (i < 262144) W1h[i] = f2h(W1[i]);
    else if (i < 393216) Wvh[i - 262144] = f2h(Wv[i - 262144]);
    else Wth[i - 393216] = f2h(Wt[i - 393216]);
  } else if (bx < 2562) {
    // w2sel[k] = sum_j wsel[j] * W2[j,k]   (fp32 exact, coalesced over k)
    const float* ws = (bx == 2560) ? Wre : Wrr;
    float* wd = (bx == 2560) ? w2re : w2rr;
    float a0 = 0.f, a1 = 0.f;
    for (int j = 0; j < 512; ++j) {
      float wv = ws[j];
      a0 += wv * W2[j * 512 + t];
      a1 += wv * W2[j * 512 + t + 256];
    }
    wd[t] = a0;
    wd[t + 256] = a1;
  } else {
    // rho_c[0] = b2.wre ; rho_c[1] = b2.wrr
    const float* ws = (bx == 2562) ? Wre : Wrr;
    float p = b2[t] * ws[t] + b2[t + 256] * ws[t + 256];
    p = wred(p);
    if ((t & 63) == 0) red[t >> 6] = p;
    __syncthreads();
    if (t == 0) rho_c[bx - 2562] = red[0] + red[1] + red[2] + red[3];
  }
}

// ================= M2 = Wsel @ W2 (fp16 out) + bcat = bsel + b2.Wsel_row ===========
__global__ __launch_bounds__(256) void m2_k(
    const float* __restrict__ Wv, const float* __restrict__ Wt,
    const float* __restrict__ W2, const float* __restrict__ b2,
    const float* __restrict__ bv, const float* __restrict__ bt,
    unsigned short* __restrict__ M2v, unsigned short* __restrict__ M2t,
    float* __restrict__ bcv, float* __restrict__ bct) {
  __shared__ float rowL[512];
  __shared__ float red[4];
  const int b = blockIdx.x, t = threadIdx.x;
  int n; const float* src; unsigned short* dst; const float* badd; float* bdst;
  if (b < 256) { n = b; src = Wv + (long)n * 512; dst = M2v + (long)n * 512; badd = bv; bdst = bcv; }
  else { n = b - 256; src = Wt + (long)n * 512; dst = M2t + (long)n * 512; badd = bt; bdst = bct; }
  rowL[t] = src[t]; rowL[t + 256] = src[t + 256];
  __syncthreads();
  float a0 = 0.f, a1 = 0.f;
  for (int j = 0; j < 512; ++j) {
    float rv = rowL[j];
    a0 += rv * W2[(long)j * 512 + t];
    a1 += rv * W2[(long)j * 512 + t + 256];
  }
  dst[t] = f2h(a0);
  dst[t + 256] = f2h(a1);
  float p = b2[t] * rowL[t] + b2[t + 256] * rowL[t + 256];
  p = wred(p);
  if ((t & 63) == 0) red[t >> 6] = p;
  __syncthreads();
  if (t == 0) bdst[n] = badd[n] + red[0] + red[1] + red[2] + red[3];
}

// ================= fused GEMM: 64-row blocks, B double-buffered through LDS ========
// 8 waves (2M x 4N). Each GEMM segment computes C[64 x 256] over K = NSTEPS*32,
// A from swizzled LDS (Xh or Ts, switching at NSTEPS/2), B staged cooperatively
// via global_load_lds into a 2 x 16KB double buffer.
// HW CAVEAT (m104/m108): global_load_lds writes LDS at uniform_base + lane*16 —
// the staging MUST be lane-contiguous. Each wave issues 2 loads covering two
// contiguous 1KB regions: chunk ci = w*128 (+64) + lane; LDS byte = ci*16;
// global src = B[ci&255][koff + (ci>>8)*8]. This realizes the layout
// [q(4)][col(256)][8 fp16]; fragment reads are then 256B-contiguous per
// 16-lane group (conflict-free).
template <int NSTEPS>
static __device__ __forceinline__ void gemm_dbuf(
    const unsigned short* A0, int ka0, const unsigned short* A1, int ka1,
    const unsigned short* __restrict__ B0g, const unsigned short* __restrict__ B1g,
    unsigned short* Bs, int tid, int w, int lane, f32x4 (&acc)[2][4]) {
  constexpr int HS = NSTEPS / 2;
  const int cg = lane >> 4, cl = lane & 15;
  const int mr = w >> 2, wc = (w & 3) * 64;
  const int ci0 = w * 128 + lane;        // chunk index, staging inst 0
  const int ci1 = w * 128 + 64 + lane;   // chunk index, staging inst 1
  const int q0 = ci0 >> 8, c0 = ci0 & 255;
  const int q1 = ci1 >> 8, c1 = ci1 & 255;

  // prologue: stage tile 0 into buf 0
  gl_lds16(B0g + (long)c0 * HH + q0 * 8, (char*)Bs + ci0 * 16);
  gl_lds16(B0g + (long)c1 * HH + q1 * 8, (char*)Bs + ci1 * 16);
  __syncthreads();

  for (int kb = 0; kb < NSTEPS; ++kb) {
    const int nkb = kb + 1;
    if (nkb < NSTEPS) {   // stage next tile into the other buffer
      const unsigned short* Bg = (nkb < HS) ? B0g : B1g;
      const int koff = (nkb & (HS - 1)) * 32;
      const int bb = (nkb & 1) * 16384;
      gl_lds16(Bg + (long)c0 * HH + koff + q0 * 8, (char*)Bs + bb + ci0 * 16);
      gl_lds16(Bg + (long)c1 * HH + koff + q1 * 8, (char*)Bs + bb + ci1 * 16);
    }
    const unsigned short* A = (kb < HS) ? A0 : A1;
    const int kA = ((kb < HS) ? ka0 : ka1) + (kb & (HS - 1)) * 32;
    f16x8 af[2], bf[4];
#pragma unroll
    for (int i = 0; i < 2; ++i) {
      const int row = mr * 32 + i * 16 + cl;
      const int bo = (row * 1024 + (kA + cg * 8) * 2) ^ ((row & 7) << 4);
      af[i] = *(const f16x8*)((const char*)A + bo);
    }
    const char* bb = (const char*)Bs + (kb & 1) * 16384 + cg * 4096;
#pragma unroll
    for (int j = 0; j < 4; ++j) bf[j] = *(const f16x8*)(bb + (wc + j * 16 + cl) * 16);
    __builtin_amdgcn_s_setprio(1);
#pragma unroll
    for (int j = 0; j < 4; ++j)
#pragma unroll
      for (int i = 0; i < 2; ++i)
        acc[i][j] = __builtin_amdgcn_mfma_f32_16x16x32_f16(af[i], bf[j], acc[i][j], 0, 0, 0);
    __builtin_amdgcn_s_setprio(0);
    __syncthreads();
  }
}

__global__ __launch_bounds__(512, 2) void fused_k(
    const float* __restrict__ x0, const float* __restrict__ x1,
    const float* __restrict__ x2, const unsigned short* __restrict__ W1h,
    const float* __restrict__ b1, const float* __restrict__ wre,
    const float* __restrict__ wrr, const float* __restrict__ w2re,
    const float* __restrict__ w2rr, const unsigned short* __restrict__ Wvh,
    const unsigned short* __restrict__ Wth, const unsigned short* __restrict__ M2v,
    const unsigned short* __restrict__ M2t, const float* __restrict__ bcv,
    const float* __restrict__ bct, unsigned short* __restrict__ Uh,
    unsigned short* __restrict__ Ut, unsigned short* __restrict__ THh,
    float* __restrict__ rho_raw) {
  __shared__ unsigned short Xh[64 * 512];  // 64 KB, swizzled
  __shared__ unsigned short Ts[64 * 512];  // 64 KB, swizzled
  __shared__ unsigned short Bs[2 * 8192];  // 32 KB B double-buffer
  const int tid = threadIdx.x, lane = tid & 63, w = tid >> 6;
  const int cg = lane >> 4, cl = lane & 15;
  const int mr = w >> 2, wc = (w & 3) * 64;
  const int bx = blockIdx.x;
  const int ent = bx % 3;                       // interleave for load balance
  const long mloc = (long)(bx / 3) * 64;
  const float* X = (ent == 0) ? x0 : (ent == 1) ? x1 : x2;
  const float* wsel = (ent < 2) ? wre : wrr;
  const float* w2sel = (ent < 2) ? w2re : w2rr;
  const long rbase = (long)ent * NB + mloc;

  // ---- phase 0: X fp32 -> fp16 Xh (swizzled), rho X-part (atomicAdd, zeroed) ----
  {
    const int col = lane * 8;  // one wave covers one full 512-col row per q
    const f32x4 wv0 = *(const f32x4*)(wsel + col);
    const f32x4 wv1 = *(const f32x4*)(wsel + col + 4);
#pragma unroll
    for (int q = 0; q < 8; ++q) {
      const int row = q * 8 + w;
      const float* gp = X + (mloc + row) * HH + col;
      const f32x4 a0 = *(const f32x4*)gp;
      const f32x4 a1 = *(const f32x4*)(gp + 4);
      f16x8 hx;
      hx[0] = (_Float16)a0[0]; hx[1] = (_Float16)a0[1];
      hx[2] = (_Float16)a0[2]; hx[3] = (_Float16)a0[3];
      hx[4] = (_Float16)a1[0]; hx[5] = (_Float16)a1[1];
      hx[6] = (_Float16)a1[2]; hx[7] = (_Float16)a1[3];
      const int bo = (row * 1024 + col * 2) ^ ((row & 7) << 4);
      *(f16x8*)((char*)Xh + bo) = hx;
      float p = a0[0] * wv0[0] + a0[1] * wv0[1] + a0[2] * wv0[2] + a0[3] * wv0[3] +
                a1[0] * wv1[0] + a1[1] * wv1[1] + a1[2] * wv1[2] + a1[3] * wv1[3];
      p = wred(p);
      if (lane == 0) atomicAdd(&rho_raw[rbase + row], p);
    }
  }
  __syncthreads();

  // ---- phase 1: T = relu(Xh @ W1h^T + b1): two 256-col halves, K=512 ----
  for (int nh = 0; nh < 2; ++nh) {
    f32x4 acc[2][4] = {};
    const unsigned short* Bb = W1h + (long)(nh * 256) * HH;
    gemm_dbuf<16>(Xh, 0, Xh, 256, Bb, Bb + 256, Bs, tid, w, lane, acc);
    float drow[2][4] = {{0.f, 0.f, 0.f, 0.f}, {0.f, 0.f, 0.f, 0.f}};
#pragma unroll
    for (int i = 0; i < 2; ++i)
#pragma unroll
      for (int j = 0; j < 4; ++j) {
        const int col = nh * 256 + wc + j * 16 + cl;
        const float bc = b1[col], w2v = w2sel[col];
#pragma unroll
        for (int r = 0; r < 4; ++r) {
          const int row = mr * 32 + i * 16 + cg * 4 + r;
          const float v = fmaxf(acc[i][j][r] + bc, 0.f);
          const int bo = (row * 1024 + col * 2) ^ ((row & 7) << 4);
          *(unsigned short*)((char*)Ts + bo) = f2h(v);
          drow[i][r] += v * w2v;
        }
      }
#pragma unroll
    for (int i = 0; i < 2; ++i)
#pragma unroll
      for (int r = 0; r < 4; ++r) {
        float s = drow[i][r];
        s += __shfl_xor(s, 1); s += __shfl_xor(s, 2);
        s += __shfl_xor(s, 4); s += __shfl_xor(s, 8);
        if (cl == 0) atomicAdd(&rho_raw[rbase + mr * 32 + i * 16 + cg * 4 + r], s);
      }
    __syncthreads();  // Ts writes visible before phase-2 reads (and next nh reuses Bs)
  }

  // ---- phase 2: heads. K=1024 = Xh half then Ts half ----
  if (ent < 2) {
    unsigned short* Out = ent ? Ut : Uh;   // ent0 = h, ent1 = t
    f32x4 acc[2][4] = {};
    gemm_dbuf<32>(Xh, 0, Ts, 0, Wvh, M2v, Bs, tid, w, lane, acc);
#pragma unroll
    for (int i = 0; i < 2; ++i)
#pragma unroll
      for (int j = 0; j < 4; ++j) {
        const int col = wc + j * 16 + cl;
        const float bc = bcv[col];
#pragma unroll
        for (int r = 0; r < 4; ++r)
          Out[(mloc + mr * 32 + i * 16 + cg * 4 + r) * 256 + col] = f2h(acc[i][j][r] + bc);
      }
  } else {
    for (int nh = 0; nh < 2; ++nh) {
      f32x4 acc[2][4] = {};
      gemm_dbuf<32>(Xh, 0, Ts, 0, Wth + (long)(nh * 256) * HH,
                    M2t + (long)(nh * 256) * HH, Bs, tid, w, lane, acc);
#pragma unroll
      for (int i = 0; i < 2; ++i)
#pragma unroll
        for (int j = 0; j < 4; ++j) {
          const int col = nh * 256 + wc + j * 16 + cl;
          const float bc = bct[col];
#pragma unroll
          for (int r = 0; r < 4; ++r)
            THh[(mloc + mr * 32 + i * 16 + cg * 4 + r) * (long)HH + col] =
                f2h(acc[i][j][r] + bc);
        }
      if (nh == 0) __syncthreads();  // Bs reuse between halves
    }
  }
}

// ================= Givens chain: wave-parallel linear scan =========================
__device__ __forceinline__ void givens_pass(float v[4], const float c[4],
                                            const float s[4], int lane) {
  float vn3 = __shfl_down(v[0], 1);
  float A = 1.f, Bc = 0.f;
#pragma unroll
  for (int k = 0; k < 4; ++k) {
    float vnext = (k < 3) ? v[k + 1] : vn3;
    bool skip = (lane == 63) && (k == 3);
    if (!skip) { Bc = s[k] * Bc + c[k] * vnext; A = s[k] * A; }
  }
  float iA = A, iB = Bc;
#pragma unroll
  for (int off = 1; off < 64; off <<= 1) {
    float pA = __shfl_up(iA, off);
    float pB = __shfl_up(iB, off);
    if (lane >= off) { iB = iA * pB + iB; iA = iA * pA; }
  }
  float eA = __shfl_up(iA, 1);
  float eB = __shfl_up(iB, 1);
  if (lane == 0) { eA = 1.f; eB = 0.f; }
  float v0g = __shfl(v[0], 0);
  float K = eA * v0g + eB;
  float out[4];
#pragma unroll
  for (int k = 0; k < 4; ++k) {
    float vnext = (k < 3) ? v[k + 1] : vn3;
    bool skip = (lane == 63) && (k == 3);
    if (!skip) {
      out[k] = c[k] * K - s[k] * vnext;
      K = s[k] * K + c[k] * vnext;
    } else out[k] = 0.f;
  }
  float K255 = __shfl(K, 63);
  float c255 = __shfl(c[3], 63);
  float s255 = __shfl(s[3], 63);
  float o0 = __shfl(out[0], 0);
  if (lane == 63) out[3] = c255 * K255 - s255 * o0;
  if (lane == 0) out[0] = s255 * K255 + c255 * o0;
  v[0] = out[0]; v[1] = out[1]; v[2] = out[2]; v[3] = out[3];
}

// ================= final per-row kernel: one wave per row ==========================
__global__ __launch_bounds__(256) void final_k(
    const unsigned short* __restrict__ Uh, const unsigned short* __restrict__ Ut,
    const unsigned short* __restrict__ THh, const float* __restrict__ rho_raw,
    const float* __restrict__ rho_c, const float* __restrict__ sim,
    const float* __restrict__ bre, const float* __restrict__ brr,
    const float* __restrict__ ga_rho, const float* __restrict__ gb_rho,
    const float* __restrict__ ga_phi, const float* __restrict__ gb_phi,
    float* __restrict__ out) {
  const int lane = threadIdx.x & 63;
  const int b = blockIdx.x * 4 + (threadIdx.x >> 6);

  us4v h4 = *(const us4v*)(Uh + (long)b * 256 + lane * 4);
  us4v t4 = *(const us4v*)(Ut + (long)b * 256 + lane * 4);
  us4v a4 = *(const us4v*)(THh + (long)b * 512 + lane * 4);
  us4v b4 = *(const us4v*)(THh + (long)b * 512 + 256 + lane * 4);

  const float PI_F = 3.14159265358979f;
  float vh[4], vt[4], cA[4], sA[4], cB[4], sB[4];
#pragma unroll
  for (int k = 0; k < 4; ++k) {
    vh[k] = h2f(h4[k]); vt[k] = h2f(t4[k]);
    float aa = PI_F * tanh_fast(h2f(a4[k]));
    sA[k] = __sinf(aa); cA[k] = __cosf(aa);
    float ab = PI_F * tanh_fast(h2f(b4[k]));
    sB[k] = __sinf(ab); cB[k] = __cosf(ab);
  }

  float ssq = wred(vh[0] * vh[0] + vh[1] * vh[1] + vh[2] * vh[2] + vh[3] * vh[3]);
  float invh = 1.f / (sqrtf(ssq) + 1e-8f);
  float u[4], v[4];
#pragma unroll
  for (int k = 0; k < 4; ++k) { u[k] = vh[k] * invh; v[k] = u[k]; }

  givens_pass(v, cA, sA, lane);  // rotations 0..255
  givens_pass(v, cB, sB, lane);  // rotations 256..511

  float ssr = wred(v[0] * v[0] + v[1] * v[1] + v[2] * v[2] + v[3] * v[3]);
  float invr = 1.f / (sqrtf(ssr) + 1e-8f);
  float ur[4];
#pragma unroll
  for (int k = 0; k < 4; ++k) ur[k] = v[k] * invr;

  float dt = wred(u[0] * ur[0] + u[1] * ur[1] + u[2] * ur[2] + u[3] * ur[3]);
  dt = fminf(fmaxf(dt, -1.f + 1e-8f), 1.f - 1e-8f);
  float omega = acosf(dt);
  float sino = sqrtf(fmaxf(1.f - dt * dt, 0.f));
  float sb = sim[b];
  float gphi = sigm(ga_phi[0] * sb + gb_phi[0]);
  float s1, s2;
  if (omega > 0.001f) {
    s1 = __sinf((1.f - gphi) * omega) / (sino + 1e-8f);
    s2 = __sinf(gphi * omega) / (sino + 1e-8f);
  } else {
    s1 = 1.f - gphi;
    s2 = gphi;
  }
  float up[4];
#pragma unroll
  for (int k = 0; k < 4; ++k) up[k] = s1 * u[k] + s2 * ur[k];
  float ssp = wred(up[0] * up[0] + up[1] * up[1] + up[2] * up[2] + up[3] * up[3]);
  float invp = 1.f / (sqrtf(ssp) + 1e-8f);
  float sst = wred(vt[0] * vt[0] + vt[1] * vt[1] + vt[2] * vt[2] + vt[3] * vt[3]);
  float invt = 1.f / (sqrtf(sst) + 1e-8f);
  float dp = wred(up[0] * vt[0] + up[1] * vt[1] + up[2] * vt[2] + up[3] * vt[3]) * invp * invt;

  float rh = fminf(fmaxf(softplus_fast(rho_raw[b] + rho_c[0] + bre[0]), 0.f), 9.f);
  float rt = fminf(fmaxf(softplus_fast(rho_raw[NB + b] + rho_c[0] + bre[0]), 0.f), 9.f);
  float dR = rho_raw[2 * NB + b] + rho_c[1] + brr[0];
  float grho = sigm(ga_rho[0] * sb + gb_rho[0]);
  float rp = fminf(fmaxf(rh + dR * grho, 0.f), 9.f);
  float er = __expf(rp), eri = __expf(-rp);
  float et = __expf(rt), eti = __expf(-rt);
  float score = -0.25f * (er + eri) * (et + eti) + 0.25f * (er - eri) * (et - eti) * dp;
  if (lane == 0) out[b] = score;
}

extern "C" void kernel_launch(void* const* d_in, const int* in_sizes, int n_in,
                              void* d_out, int out_size, void* d_ws, size_t ws_size,
                              hipStream_t stream) {
  (void)in_sizes; (void)n_in;
  const float* x0 = (const float*)d_in[0];   // ent_embed (h)
  const float* x2 = (const float*)d_in[1];   // rel_embed (r)
  const float* x1 = (const float*)d_in[2];   // ent_label (t)
  const float* sim = (const float*)d_in[3];
  const float* Wv = (const float*)d_in[4];
  const float* bv = (const float*)d_in[5];
  const float* Wre = (const float*)d_in[6];
  const float* bre = (const float*)d_in[7];
  const float* Wrr = (const float*)d_in[8];
  const float* brr = (const float*)d_in[9];
  const float* Wt = (const float*)d_in[10];
  const float* bt = (const float*)d_in[11];
  const float* ga_rho = (const float*)d_in[12];
  const float* gb_rho = (const float*)d_in[13];
  const float* ga_phi = (const float*)d_in[14];
  const float* gb_phi = (const float*)d_in[15];
  const float* W1 = (const float*)d_in[16];
  const float* b1 = (const float*)d_in[17];
  const float* W2 = (const float*)d_in[18];
  const float* b2 = (const float*)d_in[19];

  const size_t NEEDED = 69606408ULL;
  if (ws_size < NEEDED) {  // clean diagnostic failure instead of OOB fault
    (void)hipMemsetAsync(d_out, 0, (size_t)out_size * sizeof(float), stream);
    return;
  }
  char* ws = (char*)d_ws;
  unsigned short* Uh = (unsigned short*)ws;                 // 16 MB (NB x 256 f16)
  unsigned short* Ut = (unsigned short*)(ws + 16777216);    // 16 MB
  unsigned short* THh = (unsigned short*)(ws + 33554432);   // 32 MB (NB x 512 f16)
  float* rho_raw = (float*)(ws + 67108864);                 // 384 KB (3*NB f32)
  unsigned short* W1h = (unsigned short*)(ws + 67502080);   // 512 KB
  unsigned short* Wvh = (unsigned short*)(ws + 68026368);   // 256 KB
  unsigned short* Wth = (unsigned short*)(ws + 68288512);   // 512 KB
  unsigned short* M2v = (unsigned short*)(ws + 68812800);   // 256 KB
  unsigned short* M2t = (unsigned short*)(ws + 69074944);   // 512 KB
  float* w2re = (float*)(ws + 69599232);                    // 2 KB
  float* w2rr = (float*)(ws + 69601280);                    // 2 KB
  float* bcv = (float*)(ws + 69603328);                     // 1 KB
  float* bct = (float*)(ws + 69604352);                     // 2 KB
  float* rho_c = (float*)(ws + 69606400);                   // 8 B

  prep_k<<<dim3(2564), dim3(256), 0, stream>>>(
      W1, Wv, Wt, Wre, Wrr, b2, W2, W1h, Wvh, Wth, rho_raw, w2re, w2rr, rho_c);

  m2_k<<<dim3(768), dim3(256), 0, stream>>>(Wv, Wt, W2, b2, bv, bt, M2v, M2t, bcv, bct);

  fused_k<<<dim3(1536), dim3(512), 0, stream>>>(
      x0, x1, x2, W1h, b1, Wre, Wrr, w2re, w2rr, Wvh, Wth, M2v, M2t, bcv, bct,
      Uh, Ut, THh, rho_raw);

  final_k<<<dim3(8192), dim3(256), 0, stream>>>(
      Uh, Ut, THh, rho_raw, rho_c, sim, bre, brr, ga_rho, gb_rho, ga_phi, gb_phi,
      (float*)d_out);
}